// Round 6
// baseline (474.195 us; speedup 1.0000x reference)
//
#include <hip/hip_runtime.h>
#include <stdint.h>

#define NN    50000
#define NE    800000
#define FD    128
#define NLAY  4
#define NLIN  256
#define NOUTF 10
#define NGR   64
#define NBKT  196     // ceil(NN/256) buckets of 256 nodes
#define MAXB  8192    // per-bucket capacity (mean 4082, sd 64 -> safe)
#define NCH   4       // feature chunks (32 feats = 64 B per plane row)

typedef _Float16 half8  __attribute__((ext_vector_type(8)));
typedef _Float16 half4  __attribute__((ext_vector_type(4)));
typedef _Float16 half2t __attribute__((ext_vector_type(2)));
typedef float    f32x4  __attribute__((ext_vector_type(4)));

// ---------------- index dtype probe ----------------
// If int64 (values < 2^31), every odd 32-bit word of edge_index is 0.
__global__ void detect_k(const unsigned* __restrict__ p, int* __restrict__ flag){
    __shared__ int any;
    if (threadIdx.x == 0) any = 0;
    __syncthreads();
    if (p[2*threadIdx.x + 1] != 0u) atomicOr(&any, 1);
    __syncthreads();
    if (threadIdx.x == 0) *flag = (any == 0) ? 1 : 0;   // 1 => int64
}

__device__ __forceinline__ int ld_idx(const void* p, int flag, long i){
    return flag ? (int)((const long long*)p)[i] : ((const int*)p)[i];
}

// ---------------- fp16 weight prep ----------------
__global__ void prep_w_k(const float* __restrict__ Ws, _Float16* __restrict__ WT){
    // WT[l][c][k] = Ws[l][k][c]
    int idx = blockIdx.x*256 + threadIdx.x;
    if (idx >= NLAY*FD*FD) return;
    int l = idx >> 14;
    int r = idx & 16383;
    int c = r >> 7, k = r & 127;
    WT[idx] = (_Float16)Ws[(l<<14) + (k<<7) + c];
}

__global__ void zero_k(int* __restrict__ p, int n){
    int i = blockIdx.x*256 + threadIdx.x;
    if (i < n) p[i] = 0;
}

// ---------------- pass B: bin edges into 196 fixed-stride bucket regions ----------------
// record = (dst&255)<<16 | src   (src < 50000 < 2^16)
__global__ __launch_bounds__(1024) void binB_k(const void* __restrict__ eidx,
                                               const int* __restrict__ flag,
                                               int* __restrict__ bktCur,
                                               unsigned* __restrict__ binned){
    __shared__ int hist[NBKT];
    __shared__ int resv[NBKT];
    __shared__ int cur[NBKT];
    const int tid = threadIdx.x;
    const int f = *flag;
    if (tid < NBKT){ hist[tid] = 0; cur[tid] = 0; }
    __syncthreads();

    int bkt[4]; unsigned pk[4];
    #pragma unroll
    for (int u = 0; u < 4; ++u){
        long e = (long)blockIdx.x*4096 + u*1024 + tid;
        if (e < NE){
            int s = ld_idx(eidx, f, e);
            int d = ld_idx(eidx, f, (long)NE + e);
            bkt[u] = d >> 8;
            pk[u]  = ((unsigned)(d & 255) << 16) | (unsigned)s;
            atomicAdd(&hist[bkt[u]], 1);
        } else bkt[u] = -1;
    }
    __syncthreads();
    if (tid < NBKT && hist[tid] > 0)
        resv[tid] = atomicAdd(&bktCur[tid], hist[tid]);
    __syncthreads();
    #pragma unroll
    for (int u = 0; u < 4; ++u){
        if (bkt[u] >= 0){
            int p = resv[bkt[u]] + atomicAdd(&cur[bkt[u]], 1);
            if (p < MAXB) binned[(long)bkt[u]*MAXB + p] = pk[u];
        }
    }
}

// ---------------- pass C: per-bucket LDS counting sort -> rp, re, dinv, cn(ushort) ----------------
__global__ __launch_bounds__(256) void passC_k(const int* __restrict__ bktCur,
                                               const unsigned* __restrict__ binned,
                                               int* __restrict__ rp, int* __restrict__ re,
                                               float* __restrict__ dinv,
                                               unsigned short* __restrict__ cn){
    __shared__ unsigned staged[MAXB];
    __shared__ int cnt[256];
    __shared__ int sc[256];
    __shared__ int cur[256];
    const int b = blockIdx.x, tid = threadIdx.x;
    int n = bktCur[b]; if (n > MAXB) n = MAXB;
    const long base = (long)b*MAXB;

    cnt[tid] = 0;
    __syncthreads();
    for (int i = tid; i < n; i += 256){
        unsigned rec = binned[base + i];
        staged[i] = rec;
        atomicAdd(&cnt[rec >> 16], 1);
    }
    __syncthreads();
    sc[tid] = cnt[tid];
    __syncthreads();
    for (int off = 1; off < 256; off <<= 1){
        int t = (tid >= off) ? sc[tid - off] : 0;
        __syncthreads();
        if (tid >= off) sc[tid] += t;
        __syncthreads();
    }
    int lo = sc[tid] - cnt[tid];
    int v = b*256 + tid;
    if (v < NN){
        rp[v]   = (int)base + lo;
        re[v]   = (int)base + lo + cnt[tid];
        dinv[v] = rsqrtf((float)(cnt[tid] + 1));
    }
    cur[tid] = lo;
    __syncthreads();
    for (int i = tid; i < n; i += 256){
        unsigned rec = staged[i];
        int j = rec >> 16;
        int p = atomicAdd(&cur[j], 1);
        cn[base + p] = (unsigned short)(rec & 0xFFFFu);
    }
}

// ---------------- graph segment boundaries (batch sorted) ----------------
__global__ void bound_k(const void* __restrict__ batv, const int* __restrict__ flag,
                        int* __restrict__ gstart){
    int i = blockIdx.x*256 + threadIdx.x;
    if (i >= NN) return;
    int f = *flag;
    int b = ld_idx(batv, f, i);
    if (i == 0){
        for (int g = 0; g <= b; ++g) gstart[g] = 0;
    } else {
        int p = ld_idx(batv, f, i-1);
        for (int g = p+1; g <= b; ++g) gstart[g] = i;
    }
    if (i == NN-1){
        for (int g = b+1; g <= NGR; ++g) gstart[g] = NN;
    }
}

// ---------------- fp16 MFMA GEMM: t' = dinv[m] * (A[M,128] @ W), stored CHUNK-MAJOR ----------------
// t layout: 4 planes of [NN][32] fp16 (3.2 MB each -> one plane fits an XCD L2).
// Block = 256 thr = 4 waves; block tile 64 rows x 128 cols; wave tile 32r x 64c.
template<bool F32IN>
__global__ __launch_bounds__(256) void gemm_k(const void* __restrict__ Av,
                                              const _Float16* __restrict__ WT,
                                              const float* __restrict__ dinv,
                                              _Float16* __restrict__ T){
    const int tid  = threadIdx.x;
    const int lane = tid & 63;
    const int wid  = tid >> 6;
    const int wr   = (wid >> 1) * 32;
    const int wc   = (wid & 1) * 64;
    const long r0  = (long)blockIdx.x * 64 + wr;
    const int lr   = lane & 15;
    const int lk   = (lane >> 4) * 8;

    half8 wf[4][4];
    #pragma unroll
    for (int n = 0; n < 4; ++n)
        #pragma unroll
        for (int kk = 0; kk < 4; ++kk)
            wf[n][kk] = *reinterpret_cast<const half8*>(WT + (wc + n*16 + lr)*FD + kk*32 + lk);

    f32x4 acc[2][4];
    #pragma unroll
    for (int m = 0; m < 2; ++m)
        #pragma unroll
        for (int n = 0; n < 4; ++n)
            acc[m][n] = (f32x4){0.f,0.f,0.f,0.f};

    #pragma unroll
    for (int kk = 0; kk < 4; ++kk){
        half8 af[2];
        #pragma unroll
        for (int m = 0; m < 2; ++m){
            long row = r0 + m*16 + lr;
            if (row < NN){
                if constexpr (F32IN){
                    const float* A = (const float*)Av;
                    float4 u0 = *reinterpret_cast<const float4*>(A + row*FD + kk*32 + lk);
                    float4 u1 = *reinterpret_cast<const float4*>(A + row*FD + kk*32 + lk + 4);
                    half8 a;
                    a[0]=(_Float16)u0.x; a[1]=(_Float16)u0.y; a[2]=(_Float16)u0.z; a[3]=(_Float16)u0.w;
                    a[4]=(_Float16)u1.x; a[5]=(_Float16)u1.y; a[6]=(_Float16)u1.z; a[7]=(_Float16)u1.w;
                    af[m] = a;
                } else {
                    const _Float16* A = (const _Float16*)Av;
                    af[m] = *reinterpret_cast<const half8*>(A + row*FD + kk*32 + lk);
                }
            } else af[m] = (half8)(_Float16)0;
        }
        #pragma unroll
        for (int m = 0; m < 2; ++m)
            #pragma unroll
            for (int n = 0; n < 4; ++n)
                acc[m][n] = __builtin_amdgcn_mfma_f32_16x16x32_f16(wf[n][kk], af[m], acc[m][n], 0, 0, 0);
    }

    #pragma unroll
    for (int m = 0; m < 2; ++m){
        long row = r0 + m*16 + lr;
        if (row >= NN) continue;
        float di = dinv[row];
        #pragma unroll
        for (int n = 0; n < 4; ++n){
            half4 o;
            o[0] = (_Float16)(acc[m][n][0] * di);
            o[1] = (_Float16)(acc[m][n][1] * di);
            o[2] = (_Float16)(acc[m][n][2] * di);
            o[3] = (_Float16)(acc[m][n][3] * di);
            // col c = wc + n*16 + (lane>>4)*4 -> plane (wc>>5)+(n>>1), in-plane (n&1)*16+(lane>>4)*4
            size_t off = (size_t)((wc >> 5) + (n >> 1)) * ((size_t)NN*32)
                       + (size_t)row*32 + (n & 1)*16 + (lane >> 4)*4;
            *reinterpret_cast<half4*>(T + off) = o;
        }
    }
}

// ---------------- aggregation, chunked: h[v][ch*32..] = relu(dinv*(sum t'[src] + t'[v]) + b) ----
// grid (12500, NCH); one wave per node per chunk. Quarter q (16 lanes) serves edge j+q;
// lane covers feature-pair fl = lane&15 of the 32-feature plane row (64 B).
__global__ __launch_bounds__(256) void agg_k(const _Float16* __restrict__ t,
                                             const int* __restrict__ rp,
                                             const int* __restrict__ re,
                                             const unsigned short* __restrict__ cn,
                                             const float* __restrict__ dinv,
                                             const float* __restrict__ bias,
                                             _Float16* __restrict__ h){
    int v = blockIdx.x*4 + (threadIdx.x >> 6);
    if (v >= NN) return;
    const int ch   = blockIdx.y;
    const int lane = threadIdx.x & 63;
    const int q    = lane >> 4;
    const int fl   = lane & 15;
    const half2t* plane = reinterpret_cast<const half2t*>(t) + (size_t)ch*NN*16;

    float a0 = 0.f, a1 = 0.f;
    if (q == 0){                     // self term (t' already dinv-scaled)
        half2t sv = plane[(long)v*16 + fl];
        a0 = (float)sv[0]; a1 = (float)sv[1];
    }

    int e0 = rp[v], e1 = re[v];
    for (int base = e0; base < e1; base += 64){
        int n = e1 - base; if (n > 64) n = 64;
        int ce = (int)cn[base + ((lane < n) ? lane : 0)];
        int j = 0;
        for (; j + 16 <= n; j += 16){
            int sA = __shfl(ce, j +      q);
            int sB = __shfl(ce, j + 4  + q);
            int sC = __shfl(ce, j + 8  + q);
            int sD = __shfl(ce, j + 12 + q);
            half2t gA = plane[(long)sA*16 + fl];
            half2t gB = plane[(long)sB*16 + fl];
            half2t gC = plane[(long)sC*16 + fl];
            half2t gD = plane[(long)sD*16 + fl];
            a0 += ((float)gA[0] + (float)gB[0]) + ((float)gC[0] + (float)gD[0]);
            a1 += ((float)gA[1] + (float)gB[1]) + ((float)gC[1] + (float)gD[1]);
        }
        for (; j < n; j += 4){
            int idx = j + q;
            int s = __shfl(ce, (idx < n) ? idx : 0);
            half2t g = plane[(long)s*16 + fl];
            if (idx < n){ a0 += (float)g[0]; a1 += (float)g[1]; }
        }
    }
    // reduce the 4 quarters
    a0 += __shfl_xor(a0, 16);  a1 += __shfl_xor(a1, 16);
    a0 += __shfl_xor(a0, 32);  a1 += __shfl_xor(a1, 32);

    if (q == 0){
        float di = dinv[v];
        float2 b = reinterpret_cast<const float2*>(bias)[ch*16 + fl];
        half2t o;
        o[0] = (_Float16)fmaxf(fmaf(a0, di, b.x), 0.f);
        o[1] = (_Float16)fmaxf(fmaf(a1, di, b.y), 0.f);
        reinterpret_cast<half2t*>(h)[(long)v*64 + ch*16 + fl] = o;
    }
}

// ---------------- per-layer global max pool: 4 waves per block + LDS reduce ----------------
__global__ __launch_bounds__(256) void pool_k(const _Float16* __restrict__ h,
                                              const int* __restrict__ gstart,
                                              unsigned* __restrict__ gbuf, int l){
    __shared__ float red[4][FD];
    int g = blockIdx.x, part = blockIdx.y;
    int tid = threadIdx.x, lane = tid & 63, w = tid >> 6;
    int s0 = gstart[g], s1 = gstart[g+1];
    int len = s1 - s0;
    int chunk = (len + 7) >> 3;
    int a = s0 + part*chunk;
    int b = min(a + chunk, s1);
    int sub = (b - a + 3) >> 2;
    int aa = a + w*sub;
    int bb = min(aa + sub, b);
    const half2t* h2 = reinterpret_cast<const half2t*>(h);
    float m0 = 0.f, m1 = 0.f;
    for (int i = aa; i < bb; ++i){
        half2t x = h2[(long)i*64 + lane];
        m0 = fmaxf(m0, (float)x[0]);
        m1 = fmaxf(m1, (float)x[1]);
    }
    red[w][2*lane]   = m0;
    red[w][2*lane+1] = m1;
    __syncthreads();
    if (w == 0){
        float r0 = fmaxf(fmaxf(red[0][2*lane],   red[1][2*lane]),
                         fmaxf(red[2][2*lane],   red[3][2*lane]));
        float r1 = fmaxf(fmaxf(red[0][2*lane+1], red[1][2*lane+1]),
                         fmaxf(red[2][2*lane+1], red[3][2*lane+1]));
        atomicMax(&gbuf[g*(NLAY*FD) + l*FD + 2*lane    ], __float_as_uint(r0));
        atomicMax(&gbuf[g*(NLAY*FD) + l*FD + 2*lane + 1], __float_as_uint(r1));
    }
}

// ---------------- head: 1024 threads/block, k-split x4 + LDS reduce ----------------
__global__ __launch_bounds__(1024) void head_k(const unsigned* __restrict__ gbuf,
                                               const float* __restrict__ Wlin,
                                               const float* __restrict__ blin,
                                               const float* __restrict__ Wout,
                                               const float* __restrict__ bout,
                                               float* __restrict__ out){
    __shared__ float gs[NLAY*FD];
    __shared__ float ps[4][NLIN];
    __shared__ float us[NLIN];
    int g = blockIdx.x, tid = threadIdx.x;
    if (tid < NLAY*FD) gs[tid] = __uint_as_float(gbuf[g*(NLAY*FD) + tid]);
    __syncthreads();
    int c = tid & 255;
    int q = tid >> 8;
    float a = 0.f;
    #pragma unroll 8
    for (int k = q*128; k < q*128 + 128; ++k)
        a = fmaf(gs[k], Wlin[k*NLIN + c], a);
    ps[q][c] = a;
    __syncthreads();
    if (tid < NLIN){
        float u = ps[0][tid] + ps[1][tid] + ps[2][tid] + ps[3][tid] + blin[tid];
        us[tid] = fmaxf(u, 0.f);
    }
    __syncthreads();
    if (tid < NOUTF){
        float o = bout[tid];
        #pragma unroll 8
        for (int k = 0; k < NLIN; ++k) o = fmaf(us[k], Wout[k*NOUTF + tid], o);
        out[g*NOUTF + tid] = o;
    }
}

// ---------------- launch ----------------
extern "C" void kernel_launch(void* const* d_in, const int* in_sizes, int n_in,
                              void* d_out, int out_size, void* d_ws, size_t ws_size,
                              hipStream_t stream){
    const float* x    = (const float*)d_in[0];
    const void*  eidx = d_in[1];
    const void*  batv = d_in[2];
    const float* Wsp  = (const float*)d_in[4];
    const float* bsp  = (const float*)d_in[5];
    const float* Wlin = (const float*)d_in[6];
    const float* blin = (const float*)d_in[7];
    const float* Wout = (const float*)d_in[8];
    const float* bout = (const float*)d_in[9];
    float* out = (float*)d_out;

    uintptr_t cur = (uintptr_t)d_ws;
    auto alloc = [&](size_t bytes)->void*{
        cur = (cur + 255) & ~(uintptr_t)255;
        void* p = (void*)cur;
        cur += bytes;
        return p;
    };
    _Float16* t    = (_Float16*)alloc((size_t)NN*FD*2);   // 4 planes [NN][32]
    _Float16* h    = (_Float16*)alloc((size_t)NN*FD*2);   // row-major [NN][128]
    _Float16* WT   = (_Float16*)alloc((size_t)NLAY*FD*FD*2);
    unsigned* binned = (unsigned*)alloc((size_t)NBKT*MAXB*4);
    unsigned short* cn = (unsigned short*)alloc((size_t)NBKT*MAXB*2);
    int*   rp    = (int*)  alloc((size_t)NN*4);
    int*   re    = (int*)  alloc((size_t)NN*4);
    float* dinv  = (float*)alloc((size_t)NN*4);
    int*   gst   = (int*)  alloc((NGR+1)*4);
    int*   flag  = (int*)  alloc(4);
    // contiguous zero region: bktCur | gbuf
    int*      bktCur = (int*)     alloc((size_t)NBKT*4);
    unsigned* gbuf   = (unsigned*)alloc((size_t)NGR*NLAY*FD*4);
    int zero_n = (int)((cur - (uintptr_t)bktCur + 3) / 4);

    detect_k<<<1, 256, 0, stream>>>((const unsigned*)eidx, flag);
    prep_w_k<<<(NLAY*FD*FD+255)/256, 256, 0, stream>>>(Wsp, WT);
    zero_k  <<<(zero_n+255)/256, 256, 0, stream>>>(bktCur, zero_n);
    binB_k  <<<NBKT, 1024, 0, stream>>>(eidx, flag, bktCur, binned);
    passC_k <<<NBKT, 256, 0, stream>>>(bktCur, binned, rp, re, dinv, cn);
    bound_k <<<(NN+255)/256, 256, 0, stream>>>(batv, flag, gst);

    for (int l = 0; l < NLAY; ++l){
        const void* hin = (l == 0) ? (const void*)x : (const void*)h;
        if (l == 0)
            gemm_k<true ><<<(NN+63)/64, 256, 0, stream>>>(hin, WT + (size_t)l*FD*FD, dinv, t);
        else
            gemm_k<false><<<(NN+63)/64, 256, 0, stream>>>(hin, WT + (size_t)l*FD*FD, dinv, t);
        agg_k <<<dim3((NN+3)/4, NCH), 256, 0, stream>>>(t, rp, re, cn, dinv, bsp + (size_t)l*FD, h);
        pool_k<<<dim3(NGR, 8), 256, 0, stream>>>(h, gst, gbuf, l);
    }
    head_k<<<NGR, 1024, 0, stream>>>(gbuf, Wlin, blin, Wout, bout, out);
}

// Round 7
// 290.055 us; speedup vs baseline: 1.6348x; 1.6348x over previous
//
#include <hip/hip_runtime.h>
#include <stdint.h>

#define NN    50000
#define NE    800000
#define FD    128
#define NLAY  4
#define NLIN  256
#define NOUTF 10
#define NGR   64
#define NBKT  196     // ceil(NN/256) buckets of 256 nodes
#define MAXB  8192    // per-bucket capacity (mean 4082, sd 64 -> safe)

typedef _Float16 half8  __attribute__((ext_vector_type(8)));
typedef _Float16 half4  __attribute__((ext_vector_type(4)));
typedef _Float16 half2t __attribute__((ext_vector_type(2)));
typedef float    f32x4  __attribute__((ext_vector_type(4)));

// ---------------- index dtype probe ----------------
// If int64 (values < 2^31), every odd 32-bit word of edge_index is 0.
__global__ void detect_k(const unsigned* __restrict__ p, int* __restrict__ flag){
    __shared__ int any;
    if (threadIdx.x == 0) any = 0;
    __syncthreads();
    if (p[2*threadIdx.x + 1] != 0u) atomicOr(&any, 1);
    __syncthreads();
    if (threadIdx.x == 0) *flag = (any == 0) ? 1 : 0;   // 1 => int64
}

__device__ __forceinline__ int ld_idx(const void* p, int flag, long i){
    return flag ? (int)((const long long*)p)[i] : ((const int*)p)[i];
}

// ---------------- fp16 weight prep ----------------
__global__ void prep_w_k(const float* __restrict__ Ws, _Float16* __restrict__ WT){
    // WT[l][c][k] = Ws[l][k][c]
    int idx = blockIdx.x*256 + threadIdx.x;
    if (idx >= NLAY*FD*FD) return;
    int l = idx >> 14;
    int r = idx & 16383;
    int c = r >> 7, k = r & 127;
    WT[idx] = (_Float16)Ws[(l<<14) + (k<<7) + c];
}

__global__ void zero_k(int* __restrict__ p, int n){
    int i = blockIdx.x*256 + threadIdx.x;
    if (i < n) p[i] = 0;
}

// ---------------- pass B: bin edges into 196 fixed-stride bucket regions ----------------
// record = (dst&255)<<16 | src   (src < 50000 < 2^16)
__global__ __launch_bounds__(1024) void binB_k(const void* __restrict__ eidx,
                                               const int* __restrict__ flag,
                                               int* __restrict__ bktCur,
                                               unsigned* __restrict__ binned){
    __shared__ int hist[NBKT];
    __shared__ int resv[NBKT];
    __shared__ int cur[NBKT];
    const int tid = threadIdx.x;
    const int f = *flag;
    if (tid < NBKT){ hist[tid] = 0; cur[tid] = 0; }
    __syncthreads();

    int bkt[4]; unsigned pk[4];
    #pragma unroll
    for (int u = 0; u < 4; ++u){
        long e = (long)blockIdx.x*4096 + u*1024 + tid;
        if (e < NE){
            int s = ld_idx(eidx, f, e);
            int d = ld_idx(eidx, f, (long)NE + e);
            bkt[u] = d >> 8;
            pk[u]  = ((unsigned)(d & 255) << 16) | (unsigned)s;
            atomicAdd(&hist[bkt[u]], 1);
        } else bkt[u] = -1;
    }
    __syncthreads();
    if (tid < NBKT && hist[tid] > 0)
        resv[tid] = atomicAdd(&bktCur[tid], hist[tid]);
    __syncthreads();
    #pragma unroll
    for (int u = 0; u < 4; ++u){
        if (bkt[u] >= 0){
            int p = resv[bkt[u]] + atomicAdd(&cur[bkt[u]], 1);
            if (p < MAXB) binned[(long)bkt[u]*MAXB + p] = pk[u];
        }
    }
}

// ---------------- pass C: per-bucket LDS counting sort -> rp, re, dinv, cn(ushort) ----------------
__global__ __launch_bounds__(256) void passC_k(const int* __restrict__ bktCur,
                                               const unsigned* __restrict__ binned,
                                               int* __restrict__ rp, int* __restrict__ re,
                                               float* __restrict__ dinv,
                                               unsigned short* __restrict__ cn){
    __shared__ unsigned staged[MAXB];
    __shared__ int cnt[256];
    __shared__ int sc[256];
    __shared__ int cur[256];
    const int b = blockIdx.x, tid = threadIdx.x;
    int n = bktCur[b]; if (n > MAXB) n = MAXB;
    const long base = (long)b*MAXB;

    cnt[tid] = 0;
    __syncthreads();
    for (int i = tid; i < n; i += 256){
        unsigned rec = binned[base + i];
        staged[i] = rec;
        atomicAdd(&cnt[rec >> 16], 1);
    }
    __syncthreads();
    sc[tid] = cnt[tid];
    __syncthreads();
    for (int off = 1; off < 256; off <<= 1){
        int t = (tid >= off) ? sc[tid - off] : 0;
        __syncthreads();
        if (tid >= off) sc[tid] += t;
        __syncthreads();
    }
    int lo = sc[tid] - cnt[tid];
    int v = b*256 + tid;
    if (v < NN){
        rp[v]   = (int)base + lo;
        re[v]   = (int)base + lo + cnt[tid];
        dinv[v] = rsqrtf((float)(cnt[tid] + 1));
    }
    cur[tid] = lo;
    __syncthreads();
    for (int i = tid; i < n; i += 256){
        unsigned rec = staged[i];
        int j = rec >> 16;
        int p = atomicAdd(&cur[j], 1);
        cn[base + p] = (unsigned short)(rec & 0xFFFFu);
    }
}

// ---------------- graph segment boundaries (batch sorted) ----------------
__global__ void bound_k(const void* __restrict__ batv, const int* __restrict__ flag,
                        int* __restrict__ gstart){
    int i = blockIdx.x*256 + threadIdx.x;
    if (i >= NN) return;
    int f = *flag;
    int b = ld_idx(batv, f, i);
    if (i == 0){
        for (int g = 0; g <= b; ++g) gstart[g] = 0;
    } else {
        int p = ld_idx(batv, f, i-1);
        for (int g = p+1; g <= b; ++g) gstart[g] = i;
    }
    if (i == NN-1){
        for (int g = b+1; g <= NGR; ++g) gstart[g] = NN;
    }
}

// ---------------- fp16 MFMA GEMM: T[M,128] = dinv[m] * (A[M,128] @ W), W as WT[c][k] ----------------
// Block = 256 thr = 4 waves; block tile 64 rows x 128 cols; wave tile 32r x 64c.
// F32IN: read A as f32 (layer 0), converting in-register.
template<bool F32IN>
__global__ __launch_bounds__(256) void gemm_k(const void* __restrict__ Av,
                                              const _Float16* __restrict__ WT,
                                              const float* __restrict__ dinv,
                                              _Float16* __restrict__ T){
    const int tid  = threadIdx.x;
    const int lane = tid & 63;
    const int wid  = tid >> 6;
    const int wr   = (wid >> 1) * 32;
    const int wc   = (wid & 1) * 64;
    const long r0  = (long)blockIdx.x * 64 + wr;
    const int lr   = lane & 15;
    const int lk   = (lane >> 4) * 8;

    half8 wf[4][4];
    #pragma unroll
    for (int n = 0; n < 4; ++n)
        #pragma unroll
        for (int kk = 0; kk < 4; ++kk)
            wf[n][kk] = *reinterpret_cast<const half8*>(WT + (wc + n*16 + lr)*FD + kk*32 + lk);

    f32x4 acc[2][4];
    #pragma unroll
    for (int m = 0; m < 2; ++m)
        #pragma unroll
        for (int n = 0; n < 4; ++n)
            acc[m][n] = (f32x4){0.f,0.f,0.f,0.f};

    #pragma unroll
    for (int kk = 0; kk < 4; ++kk){
        half8 af[2];
        #pragma unroll
        for (int m = 0; m < 2; ++m){
            long row = r0 + m*16 + lr;
            if (row < NN){
                if constexpr (F32IN){
                    const float* A = (const float*)Av;
                    float4 u0 = *reinterpret_cast<const float4*>(A + row*FD + kk*32 + lk);
                    float4 u1 = *reinterpret_cast<const float4*>(A + row*FD + kk*32 + lk + 4);
                    half8 a;
                    a[0]=(_Float16)u0.x; a[1]=(_Float16)u0.y; a[2]=(_Float16)u0.z; a[3]=(_Float16)u0.w;
                    a[4]=(_Float16)u1.x; a[5]=(_Float16)u1.y; a[6]=(_Float16)u1.z; a[7]=(_Float16)u1.w;
                    af[m] = a;
                } else {
                    const _Float16* A = (const _Float16*)Av;
                    af[m] = *reinterpret_cast<const half8*>(A + row*FD + kk*32 + lk);
                }
            } else af[m] = (half8)(_Float16)0;
        }
        #pragma unroll
        for (int m = 0; m < 2; ++m)
            #pragma unroll
            for (int n = 0; n < 4; ++n)
                acc[m][n] = __builtin_amdgcn_mfma_f32_16x16x32_f16(wf[n][kk], af[m], acc[m][n], 0, 0, 0);
    }

    #pragma unroll
    for (int m = 0; m < 2; ++m){
        long row = r0 + m*16 + lr;
        if (row >= NN) continue;
        float di = dinv[row];
        #pragma unroll
        for (int n = 0; n < 4; ++n){
            half4 o;
            o[0] = (_Float16)(acc[m][n][0] * di);
            o[1] = (_Float16)(acc[m][n][1] * di);
            o[2] = (_Float16)(acc[m][n][2] * di);
            o[3] = (_Float16)(acc[m][n][3] * di);
            *reinterpret_cast<half4*>(T + row*FD + wc + n*16 + (lane>>4)*4) = o;
        }
    }
}

// ---------------- aggregation: h[v] = relu(dinv[v]*(sum_e t'[src] + t'[v]) + b) ----------------
// One wave per node. Quarter-wave gathers: 16 lanes x 16 B = one full 256 B row per quarter,
// so ONE wave-load instruction gathers 4 edges. Lane accumulates 8 f32; cross-quarter
// shfl_xor(16,32) reduce; lanes 0-15 write half8.
__global__ __launch_bounds__(256) void agg_k(const _Float16* __restrict__ t,
                                             const int* __restrict__ rp,
                                             const int* __restrict__ re,
                                             const unsigned short* __restrict__ cn,
                                             const float* __restrict__ dinv,
                                             const float* __restrict__ bias,
                                             _Float16* __restrict__ h){
    int v = blockIdx.x*4 + (threadIdx.x >> 6);
    if (v >= NN) return;
    const int lane = threadIdx.x & 63;
    const int q = lane >> 4;      // quarter: which edge of the group of 4
    const int r = lane & 15;      // 16 B slot within the row
    const half8* t8 = reinterpret_cast<const half8*>(t);   // row stride = 16 half8

    float acc[8];
    #pragma unroll
    for (int i = 0; i < 8; ++i) acc[i] = 0.f;

    int e0 = rp[v], e1 = re[v];
    for (int base = e0; base < e1; base += 64){
        int n = e1 - base; if (n > 64) n = 64;
        int ce = (int)cn[base + ((lane < n) ? lane : 0)];
        int j = 0;
        for (; j + 8 <= n; j += 8){
            int sA = __shfl(ce, j + q);
            int sB = __shfl(ce, j + 4 + q);
            half8 gA = t8[(size_t)sA*16 + r];
            half8 gB = t8[(size_t)sB*16 + r];
            #pragma unroll
            for (int i = 0; i < 8; ++i)
                acc[i] += (float)gA[i] + (float)gB[i];
        }
        for (; j < n; j += 4){
            int idx = j + q;
            int s = __shfl(ce, (idx < n) ? idx : 0);
            half8 g = t8[(size_t)s*16 + r];
            if (idx < n){
                #pragma unroll
                for (int i = 0; i < 8; ++i) acc[i] += (float)g[i];
            }
        }
    }
    // reduce the 4 quarters
    #pragma unroll
    for (int i = 0; i < 8; ++i){
        acc[i] += __shfl_xor(acc[i], 16);
        acc[i] += __shfl_xor(acc[i], 32);
    }

    if (q == 0){
        half8 sv = t8[(size_t)v*16 + r];       // self term (already dinv-scaled)
        float di = dinv[v];
        float4 b0 = reinterpret_cast<const float4*>(bias)[2*r];
        float4 b1 = reinterpret_cast<const float4*>(bias)[2*r+1];
        float bb[8] = {b0.x,b0.y,b0.z,b0.w,b1.x,b1.y,b1.z,b1.w};
        half8 o;
        #pragma unroll
        for (int i = 0; i < 8; ++i)
            o[i] = (_Float16)fmaxf(fmaf(acc[i] + (float)sv[i], di, bb[i]), 0.f);
        reinterpret_cast<half8*>(h)[(size_t)v*16 + r] = o;
    }
}

// ---------------- per-layer global max pool: 4 waves per block + LDS reduce ----------------
__global__ __launch_bounds__(256) void pool_k(const _Float16* __restrict__ h,
                                              const int* __restrict__ gstart,
                                              unsigned* __restrict__ gbuf, int l){
    __shared__ float red[4][FD];
    int g = blockIdx.x, part = blockIdx.y;
    int tid = threadIdx.x, lane = tid & 63, w = tid >> 6;
    int s0 = gstart[g], s1 = gstart[g+1];
    int len = s1 - s0;
    int chunk = (len + 7) >> 3;
    int a = s0 + part*chunk;
    int b = min(a + chunk, s1);
    int sub = (b - a + 3) >> 2;
    int aa = a + w*sub;
    int bb = min(aa + sub, b);
    const half2t* h2 = reinterpret_cast<const half2t*>(h);
    float m0 = 0.f, m1 = 0.f;
    for (int i = aa; i < bb; ++i){
        half2t x = h2[(long)i*64 + lane];
        m0 = fmaxf(m0, (float)x[0]);
        m1 = fmaxf(m1, (float)x[1]);
    }
    red[w][2*lane]   = m0;
    red[w][2*lane+1] = m1;
    __syncthreads();
    if (w == 0){
        float r0 = fmaxf(fmaxf(red[0][2*lane],   red[1][2*lane]),
                         fmaxf(red[2][2*lane],   red[3][2*lane]));
        float r1 = fmaxf(fmaxf(red[0][2*lane+1], red[1][2*lane+1]),
                         fmaxf(red[2][2*lane+1], red[3][2*lane+1]));
        atomicMax(&gbuf[g*(NLAY*FD) + l*FD + 2*lane    ], __float_as_uint(r0));
        atomicMax(&gbuf[g*(NLAY*FD) + l*FD + 2*lane + 1], __float_as_uint(r1));
    }
}

// ---------------- head: 1024 threads/block, k-split x4 + LDS reduce ----------------
__global__ __launch_bounds__(1024) void head_k(const unsigned* __restrict__ gbuf,
                                               const float* __restrict__ Wlin,
                                               const float* __restrict__ blin,
                                               const float* __restrict__ Wout,
                                               const float* __restrict__ bout,
                                               float* __restrict__ out){
    __shared__ float gs[NLAY*FD];
    __shared__ float ps[4][NLIN];
    __shared__ float us[NLIN];
    int g = blockIdx.x, tid = threadIdx.x;
    if (tid < NLAY*FD) gs[tid] = __uint_as_float(gbuf[g*(NLAY*FD) + tid]);
    __syncthreads();
    int c = tid & 255;
    int q = tid >> 8;
    float a = 0.f;
    #pragma unroll 8
    for (int k = q*128; k < q*128 + 128; ++k)
        a = fmaf(gs[k], Wlin[k*NLIN + c], a);
    ps[q][c] = a;
    __syncthreads();
    if (tid < NLIN){
        float u = ps[0][tid] + ps[1][tid] + ps[2][tid] + ps[3][tid] + blin[tid];
        us[tid] = fmaxf(u, 0.f);
    }
    __syncthreads();
    if (tid < NOUTF){
        float o = bout[tid];
        #pragma unroll 8
        for (int k = 0; k < NLIN; ++k) o = fmaf(us[k], Wout[k*NOUTF + tid], o);
        out[g*NOUTF + tid] = o;
    }
}

// ---------------- launch ----------------
extern "C" void kernel_launch(void* const* d_in, const int* in_sizes, int n_in,
                              void* d_out, int out_size, void* d_ws, size_t ws_size,
                              hipStream_t stream){
    const float* x    = (const float*)d_in[0];
    const void*  eidx = d_in[1];
    const void*  batv = d_in[2];
    const float* Wsp  = (const float*)d_in[4];
    const float* bsp  = (const float*)d_in[5];
    const float* Wlin = (const float*)d_in[6];
    const float* blin = (const float*)d_in[7];
    const float* Wout = (const float*)d_in[8];
    const float* bout = (const float*)d_in[9];
    float* out = (float*)d_out;

    uintptr_t cur = (uintptr_t)d_ws;
    auto alloc = [&](size_t bytes)->void*{
        cur = (cur + 255) & ~(uintptr_t)255;
        void* p = (void*)cur;
        cur += bytes;
        return p;
    };
    _Float16* t    = (_Float16*)alloc((size_t)NN*FD*2);   // row-major [NN][128]
    _Float16* h    = (_Float16*)alloc((size_t)NN*FD*2);   // row-major [NN][128]
    _Float16* WT   = (_Float16*)alloc((size_t)NLAY*FD*FD*2);
    unsigned* binned = (unsigned*)alloc((size_t)NBKT*MAXB*4);
    unsigned short* cn = (unsigned short*)alloc((size_t)NBKT*MAXB*2);
    int*   rp    = (int*)  alloc((size_t)NN*4);
    int*   re    = (int*)  alloc((size_t)NN*4);
    float* dinv  = (float*)alloc((size_t)NN*4);
    int*   gst   = (int*)  alloc((NGR+1)*4);
    int*   flag  = (int*)  alloc(4);
    // contiguous zero region: bktCur | gbuf
    int*      bktCur = (int*)     alloc((size_t)NBKT*4);
    unsigned* gbuf   = (unsigned*)alloc((size_t)NGR*NLAY*FD*4);
    int zero_n = (int)((cur - (uintptr_t)bktCur + 3) / 4);

    detect_k<<<1, 256, 0, stream>>>((const unsigned*)eidx, flag);
    prep_w_k<<<(NLAY*FD*FD+255)/256, 256, 0, stream>>>(Wsp, WT);
    zero_k  <<<(zero_n+255)/256, 256, 0, stream>>>(bktCur, zero_n);
    binB_k  <<<NBKT, 1024, 0, stream>>>(eidx, flag, bktCur, binned);
    passC_k <<<NBKT, 256, 0, stream>>>(bktCur, binned, rp, re, dinv, cn);
    bound_k <<<(NN+255)/256, 256, 0, stream>>>(batv, flag, gst);

    for (int l = 0; l < NLAY; ++l){
        const void* hin = (l == 0) ? (const void*)x : (const void*)h;
        if (l == 0)
            gemm_k<true ><<<(NN+63)/64, 256, 0, stream>>>(hin, WT + (size_t)l*FD*FD, dinv, t);
        else
            gemm_k<false><<<(NN+63)/64, 256, 0, stream>>>(hin, WT + (size_t)l*FD*FD, dinv, t);
        agg_k <<<(NN+3)/4, 256, 0, stream>>>(t, rp, re, cn, dinv, bsp + (size_t)l*FD, h);
        pool_k<<<dim3(NGR, 8), 256, 0, stream>>>(h, gst, gbuf, l);
    }
    head_k<<<NGR, 1024, 0, stream>>>(gbuf, Wlin, blin, Wout, bout, out);
}

// Round 8
// 287.299 us; speedup vs baseline: 1.6505x; 1.0096x over previous
//
#include <hip/hip_runtime.h>
#include <stdint.h>

#define NN    50000
#define NE    800000
#define FD    128
#define NLAY  4
#define NLIN  256
#define NOUTF 10
#define NGR   64
#define NBKT  196     // ceil(NN/256) buckets of 256 nodes
#define MAXB  8192    // per-bucket capacity (mean 4082, sd 64 -> safe)

typedef _Float16 half8  __attribute__((ext_vector_type(8)));
typedef _Float16 half4  __attribute__((ext_vector_type(4)));
typedef _Float16 half2t __attribute__((ext_vector_type(2)));
typedef float    f32x4  __attribute__((ext_vector_type(4)));

// ---------------- index dtype probe ----------------
// If int64 (values < 2^31), every odd 32-bit word of edge_index is 0.
__global__ void detect_k(const unsigned* __restrict__ p, int* __restrict__ flag){
    __shared__ int any;
    if (threadIdx.x == 0) any = 0;
    __syncthreads();
    if (p[2*threadIdx.x + 1] != 0u) atomicOr(&any, 1);
    __syncthreads();
    if (threadIdx.x == 0) *flag = (any == 0) ? 1 : 0;   // 1 => int64
}

__device__ __forceinline__ int ld_idx(const void* p, int flag, long i){
    return flag ? (int)((const long long*)p)[i] : ((const int*)p)[i];
}

// ---------------- fp16 weight prep ----------------
__global__ void prep_w_k(const float* __restrict__ Ws, _Float16* __restrict__ WT){
    // WT[l][c][k] = Ws[l][k][c]
    int idx = blockIdx.x*256 + threadIdx.x;
    if (idx >= NLAY*FD*FD) return;
    int l = idx >> 14;
    int r = idx & 16383;
    int c = r >> 7, k = r & 127;
    WT[idx] = (_Float16)Ws[(l<<14) + (k<<7) + c];
}

__global__ void zero_k(int* __restrict__ p, int n){
    int i = blockIdx.x*256 + threadIdx.x;
    if (i < n) p[i] = 0;
}

// ---------------- pass B: bin edges into 196 fixed-stride bucket regions ----------------
// record = (dst&255)<<16 | src   (src < 50000 < 2^16)
__global__ __launch_bounds__(1024) void binB_k(const void* __restrict__ eidx,
                                               const int* __restrict__ flag,
                                               int* __restrict__ bktCur,
                                               unsigned* __restrict__ binned){
    __shared__ int hist[NBKT];
    __shared__ int resv[NBKT];
    __shared__ int cur[NBKT];
    const int tid = threadIdx.x;
    const int f = *flag;
    if (tid < NBKT){ hist[tid] = 0; cur[tid] = 0; }
    __syncthreads();

    int bkt[4]; unsigned pk[4];
    #pragma unroll
    for (int u = 0; u < 4; ++u){
        long e = (long)blockIdx.x*4096 + u*1024 + tid;
        if (e < NE){
            int s = ld_idx(eidx, f, e);
            int d = ld_idx(eidx, f, (long)NE + e);
            bkt[u] = d >> 8;
            pk[u]  = ((unsigned)(d & 255) << 16) | (unsigned)s;
            atomicAdd(&hist[bkt[u]], 1);
        } else bkt[u] = -1;
    }
    __syncthreads();
    if (tid < NBKT && hist[tid] > 0)
        resv[tid] = atomicAdd(&bktCur[tid], hist[tid]);
    __syncthreads();
    #pragma unroll
    for (int u = 0; u < 4; ++u){
        if (bkt[u] >= 0){
            int p = resv[bkt[u]] + atomicAdd(&cur[bkt[u]], 1);
            if (p < MAXB) binned[(long)bkt[u]*MAXB + p] = pk[u];
        }
    }
}

// ---------------- pass C: per-bucket LDS counting sort -> rp, re, dinv, cn(ushort) ----------------
__global__ __launch_bounds__(256) void passC_k(const int* __restrict__ bktCur,
                                               const unsigned* __restrict__ binned,
                                               int* __restrict__ rp, int* __restrict__ re,
                                               float* __restrict__ dinv,
                                               unsigned short* __restrict__ cn){
    __shared__ unsigned staged[MAXB];
    __shared__ int cnt[256];
    __shared__ int sc[256];
    __shared__ int cur[256];
    const int b = blockIdx.x, tid = threadIdx.x;
    int n = bktCur[b]; if (n > MAXB) n = MAXB;
    const long base = (long)b*MAXB;

    cnt[tid] = 0;
    __syncthreads();
    for (int i = tid; i < n; i += 256){
        unsigned rec = binned[base + i];
        staged[i] = rec;
        atomicAdd(&cnt[rec >> 16], 1);
    }
    __syncthreads();
    sc[tid] = cnt[tid];
    __syncthreads();
    for (int off = 1; off < 256; off <<= 1){
        int t = (tid >= off) ? sc[tid - off] : 0;
        __syncthreads();
        if (tid >= off) sc[tid] += t;
        __syncthreads();
    }
    int lo = sc[tid] - cnt[tid];
    int v = b*256 + tid;
    if (v < NN){
        rp[v]   = (int)base + lo;
        re[v]   = (int)base + lo + cnt[tid];
        dinv[v] = rsqrtf((float)(cnt[tid] + 1));
    }
    cur[tid] = lo;
    __syncthreads();
    for (int i = tid; i < n; i += 256){
        unsigned rec = staged[i];
        int j = rec >> 16;
        int p = atomicAdd(&cur[j], 1);
        cn[base + p] = (unsigned short)(rec & 0xFFFFu);
    }
}

// ---------------- graph segment boundaries (batch sorted) ----------------
__global__ void bound_k(const void* __restrict__ batv, const int* __restrict__ flag,
                        int* __restrict__ gstart){
    int i = blockIdx.x*256 + threadIdx.x;
    if (i >= NN) return;
    int f = *flag;
    int b = ld_idx(batv, f, i);
    if (i == 0){
        for (int g = 0; g <= b; ++g) gstart[g] = 0;
    } else {
        int p = ld_idx(batv, f, i-1);
        for (int g = p+1; g <= b; ++g) gstart[g] = i;
    }
    if (i == NN-1){
        for (int g = b+1; g <= NGR; ++g) gstart[g] = NN;
    }
}

// ---------------- fp16 MFMA GEMM: T[M,128] = dinv[m] * (A[M,128] @ W), W as WT[c][k] ----------------
// Block = 256 thr = 4 waves; block tile 64 rows x 128 cols; wave tile 32r x 64c.
// F32IN: read A as f32 (layer 0), converting in-register.
template<bool F32IN>
__global__ __launch_bounds__(256) void gemm_k(const void* __restrict__ Av,
                                              const _Float16* __restrict__ WT,
                                              const float* __restrict__ dinv,
                                              _Float16* __restrict__ T){
    const int tid  = threadIdx.x;
    const int lane = tid & 63;
    const int wid  = tid >> 6;
    const int wr   = (wid >> 1) * 32;
    const int wc   = (wid & 1) * 64;
    const long r0  = (long)blockIdx.x * 64 + wr;
    const int lr   = lane & 15;
    const int lk   = (lane >> 4) * 8;

    half8 wf[4][4];
    #pragma unroll
    for (int n = 0; n < 4; ++n)
        #pragma unroll
        for (int kk = 0; kk < 4; ++kk)
            wf[n][kk] = *reinterpret_cast<const half8*>(WT + (wc + n*16 + lr)*FD + kk*32 + lk);

    f32x4 acc[2][4];
    #pragma unroll
    for (int m = 0; m < 2; ++m)
        #pragma unroll
        for (int n = 0; n < 4; ++n)
            acc[m][n] = (f32x4){0.f,0.f,0.f,0.f};

    #pragma unroll
    for (int kk = 0; kk < 4; ++kk){
        half8 af[2];
        #pragma unroll
        for (int m = 0; m < 2; ++m){
            long row = r0 + m*16 + lr;
            if (row < NN){
                if constexpr (F32IN){
                    const float* A = (const float*)Av;
                    float4 u0 = *reinterpret_cast<const float4*>(A + row*FD + kk*32 + lk);
                    float4 u1 = *reinterpret_cast<const float4*>(A + row*FD + kk*32 + lk + 4);
                    half8 a;
                    a[0]=(_Float16)u0.x; a[1]=(_Float16)u0.y; a[2]=(_Float16)u0.z; a[3]=(_Float16)u0.w;
                    a[4]=(_Float16)u1.x; a[5]=(_Float16)u1.y; a[6]=(_Float16)u1.z; a[7]=(_Float16)u1.w;
                    af[m] = a;
                } else {
                    const _Float16* A = (const _Float16*)Av;
                    af[m] = *reinterpret_cast<const half8*>(A + row*FD + kk*32 + lk);
                }
            } else af[m] = (half8)(_Float16)0;
        }
        #pragma unroll
        for (int m = 0; m < 2; ++m)
            #pragma unroll
            for (int n = 0; n < 4; ++n)
                acc[m][n] = __builtin_amdgcn_mfma_f32_16x16x32_f16(wf[n][kk], af[m], acc[m][n], 0, 0, 0);
    }

    #pragma unroll
    for (int m = 0; m < 2; ++m){
        long row = r0 + m*16 + lr;
        if (row >= NN) continue;
        float di = dinv[row];
        #pragma unroll
        for (int n = 0; n < 4; ++n){
            half4 o;
            o[0] = (_Float16)(acc[m][n][0] * di);
            o[1] = (_Float16)(acc[m][n][1] * di);
            o[2] = (_Float16)(acc[m][n][2] * di);
            o[3] = (_Float16)(acc[m][n][3] * di);
            *reinterpret_cast<half4*>(T + row*FD + wc + n*16 + (lane>>4)*4) = o;
        }
    }
}

// ---------------- aggregation: h[v] = relu(dinv[v]*(sum_e t'[src] + t'[v]) + b) ----------------
// One wave per node. 16 edges per inner iter = 4 independent wave-gathers in flight
// (quarter q covers edges j+4k+q). Out-of-range slots clamp to zero-sentinel row NN.
__global__ __launch_bounds__(256) void agg_k(const _Float16* __restrict__ t,
                                             const int* __restrict__ rp,
                                             const int* __restrict__ re,
                                             const unsigned short* __restrict__ cn,
                                             const float* __restrict__ dinv,
                                             const float* __restrict__ bias,
                                             _Float16* __restrict__ h){
    int v = blockIdx.x*4 + (threadIdx.x >> 6);
    if (v >= NN) return;
    const int lane = threadIdx.x & 63;
    const int q = lane >> 4;      // quarter: which edge of each group of 4
    const int r = lane & 15;      // 16 B slot within the row
    const half8* t8 = reinterpret_cast<const half8*>(t);   // row stride = 16 half8

    float acc[8];
    #pragma unroll
    for (int i = 0; i < 8; ++i) acc[i] = 0.f;

    int e0 = rp[v], e1 = re[v];
    for (int base = e0; base < e1; base += 64){
        int n = e1 - base; if (n > 64) n = 64;
        int ce = (int)cn[base + ((lane < n) ? lane : 0)];
        for (int j = 0; j < n; j += 16){
            int i0 = j + q, i1 = j + 4 + q, i2 = j + 8 + q, i3 = j + 12 + q;
            int s0 = __shfl(ce, i0); s0 = (i0 < n) ? s0 : NN;
            int s1 = __shfl(ce, i1); s1 = (i1 < n) ? s1 : NN;
            int s2 = __shfl(ce, i2); s2 = (i2 < n) ? s2 : NN;
            int s3 = __shfl(ce, i3); s3 = (i3 < n) ? s3 : NN;
            half8 g0 = t8[(size_t)s0*16 + r];
            half8 g1 = t8[(size_t)s1*16 + r];
            half8 g2 = t8[(size_t)s2*16 + r];
            half8 g3 = t8[(size_t)s3*16 + r];
            #pragma unroll
            for (int i = 0; i < 8; ++i)
                acc[i] += ((float)g0[i] + (float)g1[i]) + ((float)g2[i] + (float)g3[i]);
        }
    }
    // reduce the 4 quarters
    #pragma unroll
    for (int i = 0; i < 8; ++i){
        acc[i] += __shfl_xor(acc[i], 16);
        acc[i] += __shfl_xor(acc[i], 32);
    }

    if (q == 0){
        half8 sv = t8[(size_t)v*16 + r];       // self term (already dinv-scaled)
        float di = dinv[v];
        float4 b0 = reinterpret_cast<const float4*>(bias)[2*r];
        float4 b1 = reinterpret_cast<const float4*>(bias)[2*r+1];
        float bb[8] = {b0.x,b0.y,b0.z,b0.w,b1.x,b1.y,b1.z,b1.w};
        half8 o;
        #pragma unroll
        for (int i = 0; i < 8; ++i)
            o[i] = (_Float16)fmaxf(fmaf(acc[i] + (float)sv[i], di, bb[i]), 0.f);
        reinterpret_cast<half8*>(h)[(size_t)v*16 + r] = o;
    }
}

// ---------------- per-layer global max pool: 4 waves per block + LDS reduce ----------------
__global__ __launch_bounds__(256) void pool_k(const _Float16* __restrict__ h,
                                              const int* __restrict__ gstart,
                                              unsigned* __restrict__ gbuf, int l){
    __shared__ float red[4][FD];
    int g = blockIdx.x, part = blockIdx.y;
    int tid = threadIdx.x, lane = tid & 63, w = tid >> 6;
    int s0 = gstart[g], s1 = gstart[g+1];
    int len = s1 - s0;
    int chunk = (len + 7) >> 3;
    int a = s0 + part*chunk;
    int b = min(a + chunk, s1);
    int sub = (b - a + 3) >> 2;
    int aa = a + w*sub;
    int bb = min(aa + sub, b);
    const half2t* h2 = reinterpret_cast<const half2t*>(h);
    float m0 = 0.f, m1 = 0.f;
    for (int i = aa; i < bb; ++i){
        half2t x = h2[(long)i*64 + lane];
        m0 = fmaxf(m0, (float)x[0]);
        m1 = fmaxf(m1, (float)x[1]);
    }
    red[w][2*lane]   = m0;
    red[w][2*lane+1] = m1;
    __syncthreads();
    if (w == 0){
        float r0 = fmaxf(fmaxf(red[0][2*lane],   red[1][2*lane]),
                         fmaxf(red[2][2*lane],   red[3][2*lane]));
        float r1 = fmaxf(fmaxf(red[0][2*lane+1], red[1][2*lane+1]),
                         fmaxf(red[2][2*lane+1], red[3][2*lane+1]));
        atomicMax(&gbuf[g*(NLAY*FD) + l*FD + 2*lane    ], __float_as_uint(r0));
        atomicMax(&gbuf[g*(NLAY*FD) + l*FD + 2*lane + 1], __float_as_uint(r1));
    }
}

// ---------------- head: 1024 threads/block, k-split x4 + LDS reduce ----------------
__global__ __launch_bounds__(1024) void head_k(const unsigned* __restrict__ gbuf,
                                               const float* __restrict__ Wlin,
                                               const float* __restrict__ blin,
                                               const float* __restrict__ Wout,
                                               const float* __restrict__ bout,
                                               float* __restrict__ out){
    __shared__ float gs[NLAY*FD];
    __shared__ float ps[4][NLIN];
    __shared__ float us[NLIN];
    int g = blockIdx.x, tid = threadIdx.x;
    if (tid < NLAY*FD) gs[tid] = __uint_as_float(gbuf[g*(NLAY*FD) + tid]);
    __syncthreads();
    int c = tid & 255;
    int q = tid >> 8;
    float a = 0.f;
    #pragma unroll 8
    for (int k = q*128; k < q*128 + 128; ++k)
        a = fmaf(gs[k], Wlin[k*NLIN + c], a);
    ps[q][c] = a;
    __syncthreads();
    if (tid < NLIN){
        float u = ps[0][tid] + ps[1][tid] + ps[2][tid] + ps[3][tid] + blin[tid];
        us[tid] = fmaxf(u, 0.f);
    }
    __syncthreads();
    if (tid < NOUTF){
        float o = bout[tid];
        #pragma unroll 8
        for (int k = 0; k < NLIN; ++k) o = fmaf(us[k], Wout[k*NOUTF + tid], o);
        out[g*NOUTF + tid] = o;
    }
}

// ---------------- launch ----------------
extern "C" void kernel_launch(void* const* d_in, const int* in_sizes, int n_in,
                              void* d_out, int out_size, void* d_ws, size_t ws_size,
                              hipStream_t stream){
    const float* x    = (const float*)d_in[0];
    const void*  eidx = d_in[1];
    const void*  batv = d_in[2];
    const float* Wsp  = (const float*)d_in[4];
    const float* bsp  = (const float*)d_in[5];
    const float* Wlin = (const float*)d_in[6];
    const float* blin = (const float*)d_in[7];
    const float* Wout = (const float*)d_in[8];
    const float* bout = (const float*)d_in[9];
    float* out = (float*)d_out;

    uintptr_t cur = (uintptr_t)d_ws;
    auto alloc = [&](size_t bytes)->void*{
        cur = (cur + 255) & ~(uintptr_t)255;
        void* p = (void*)cur;
        cur += bytes;
        return p;
    };
    _Float16* t    = (_Float16*)alloc((size_t)(NN+1)*FD*2); // row-major + zero-sentinel row NN
    _Float16* h    = (_Float16*)alloc((size_t)NN*FD*2);     // row-major [NN][128]
    _Float16* WT   = (_Float16*)alloc((size_t)NLAY*FD*FD*2);
    unsigned* binned = (unsigned*)alloc((size_t)NBKT*MAXB*4);
    unsigned short* cn = (unsigned short*)alloc((size_t)NBKT*MAXB*2);
    int*   rp    = (int*)  alloc((size_t)NN*4);
    int*   re    = (int*)  alloc((size_t)NN*4);
    float* dinv  = (float*)alloc((size_t)NN*4);
    int*   gst   = (int*)  alloc((NGR+1)*4);
    int*   flag  = (int*)  alloc(4);
    // contiguous zero region: bktCur | gbuf
    int*      bktCur = (int*)     alloc((size_t)NBKT*4);
    unsigned* gbuf   = (unsigned*)alloc((size_t)NGR*NLAY*FD*4);
    int zero_n = (int)((cur - (uintptr_t)bktCur + 3) / 4);

    detect_k<<<1, 256, 0, stream>>>((const unsigned*)eidx, flag);
    prep_w_k<<<(NLAY*FD*FD+255)/256, 256, 0, stream>>>(Wsp, WT);
    zero_k  <<<(zero_n+255)/256, 256, 0, stream>>>(bktCur, zero_n);
    zero_k  <<<1, 256, 0, stream>>>((int*)(t + (size_t)NN*FD), FD/2);   // sentinel row
    binB_k  <<<NBKT, 1024, 0, stream>>>(eidx, flag, bktCur, binned);
    passC_k <<<NBKT, 256, 0, stream>>>(bktCur, binned, rp, re, dinv, cn);
    bound_k <<<(NN+255)/256, 256, 0, stream>>>(batv, flag, gst);

    for (int l = 0; l < NLAY; ++l){
        const void* hin = (l == 0) ? (const void*)x : (const void*)h;
        if (l == 0)
            gemm_k<true ><<<(NN+63)/64, 256, 0, stream>>>(hin, WT + (size_t)l*FD*FD, dinv, t);
        else
            gemm_k<false><<<(NN+63)/64, 256, 0, stream>>>(hin, WT + (size_t)l*FD*FD, dinv, t);
        agg_k <<<(NN+3)/4, 256, 0, stream>>>(t, rp, re, cn, dinv, bsp + (size_t)l*FD, h);
        pool_k<<<dim3(NGR, 8), 256, 0, stream>>>(h, gst, gbuf, l);
    }
    head_k<<<NGR, 1024, 0, stream>>>(gbuf, Wlin, blin, Wout, bout, out);
}